// Round 2
// baseline (767.892 us; speedup 1.0000x reference)
//
#include <hip/hip_runtime.h>
#include <cstdint>
#include <cstddef>

// ---------------------------------------------------------------------------
// TransformerEncoderLayer on MI355X (gfx950)
// B=2, S=2048, D_MODEL=1024, 16 heads x 64, VOCAB=32000, PAD=0
// bf16 MFMA for all GEMMs + flash attention; fp32 LN / residual streams.
// R2: attention rewritten barrier-free — single-wave blocks, K/V fragments
//     direct from L1/L2, LDS only for wave-local P round-trip.
// ---------------------------------------------------------------------------

#define SEQ     2048
#define NTOK    4096          // B*S
#define DMODEL  1024
#define NHEAD   16
#define DHEAD   64
#define NEGV    (-1000000000.0f)
#define LN_EPS  1e-5f

typedef __bf16 bf16_t;
typedef __bf16 bf16x8 __attribute__((ext_vector_type(8)));
typedef float  f32x4  __attribute__((ext_vector_type(4)));

#define MFMA_BF16(a,b,c) __builtin_amdgcn_mfma_f32_16x16x32_bf16((a),(b),(c),0,0,0)

__device__ __forceinline__ void gload_lds16(const void* g, void* l) {
  __builtin_amdgcn_global_load_lds(
      (__attribute__((address_space(1))) void*)(g),
      (__attribute__((address_space(3))) void*)(l), 16, 0, 0);
}

// ---------------- weight transpose+convert: W[K][N] f32 -> WT[N][K] bf16 ----
__global__ __launch_bounds__(256)
void wtrans_kernel(const float* __restrict__ W, bf16_t* __restrict__ WT,
                   int K, int N) {
  __shared__ float tile[64][65];
  const int n0 = blockIdx.x * 64, k0 = blockIdx.y * 64;
  const int c = threadIdx.x & 63, rb = threadIdx.x >> 6;
#pragma unroll
  for (int i = 0; i < 16; ++i) {
    int r = i * 4 + rb;
    tile[r][c] = W[(size_t)(k0 + r) * N + n0 + c];
  }
  __syncthreads();
#pragma unroll
  for (int i = 0; i < 16; ++i) {
    int r = i * 4 + rb;                       // output row (n), col (k)
    WT[(size_t)(n0 + r) * K + k0 + c] = (bf16_t)tile[c][r];
  }
}

__global__ __launch_bounds__(256)
void pack_bias_kernel(const float* __restrict__ bq, const float* __restrict__ bk,
                      const float* __restrict__ bv, float* __restrict__ o) {
  int i = blockIdx.x * 256 + threadIdx.x;
  if (i < 1024) { o[i] = bq[i]; o[1024 + i] = bk[i]; o[2048 + i] = bv[i]; }
}

// ---------------- embed + pos + LN1 -> x_ln f32, x_ln bf16 ------------------
__global__ __launch_bounds__(256)
void ln1_kernel(const int* __restrict__ tokens, const float* __restrict__ emb,
                const float* __restrict__ pos, const float* __restrict__ g,
                const float* __restrict__ bb, float* __restrict__ xln,
                bf16_t* __restrict__ xlnb) {
  __shared__ float red[8];
  const int t = blockIdx.x;
  const int s = t & (SEQ - 1);
  const int tok = tokens[t];
  const int d0 = threadIdx.x * 4;
  const int w = threadIdx.x >> 6, lane = threadIdx.x & 63;

  float4 e  = *(const float4*)(emb + (size_t)tok * DMODEL + d0);
  float4 pp = *(const float4*)(pos + (size_t)s   * DMODEL + d0);
  float x0 = e.x + pp.x, x1 = e.y + pp.y, x2v = e.z + pp.z, x3v = e.w + pp.w;
  float s1 = x0 + x1 + x2v + x3v;
  float s2 = x0*x0 + x1*x1 + x2v*x2v + x3v*x3v;
#pragma unroll
  for (int o = 32; o >= 1; o >>= 1) { s1 += __shfl_xor(s1, o); s2 += __shfl_xor(s2, o); }
  if (lane == 0) { red[w] = s1; red[4 + w] = s2; }
  __syncthreads();
  s1 = red[0] + red[1] + red[2] + red[3];
  s2 = red[4] + red[5] + red[6] + red[7];
  float mean = s1 * (1.0f / DMODEL);
  float var  = s2 * (1.0f / DMODEL) - mean * mean;
  float inv  = rsqrtf(var + LN_EPS);
  float4 gv = *(const float4*)(g + d0);
  float4 bv = *(const float4*)(bb + d0);
  float y0 = (x0  - mean) * inv * gv.x + bv.x;
  float y1 = (x1  - mean) * inv * gv.y + bv.y;
  float y2 = (x2v - mean) * inv * gv.z + bv.z;
  float y3 = (x3v - mean) * inv * gv.w + bv.w;
  *(float4*)(xln + (size_t)t * DMODEL + d0) = make_float4(y0, y1, y2, y3);
  union { ushort4 u; bf16_t b[4]; } cv;
  cv.b[0] = (bf16_t)y0; cv.b[1] = (bf16_t)y1; cv.b[2] = (bf16_t)y2; cv.b[3] = (bf16_t)y3;
  *(ushort4*)(xlnb + (size_t)t * DMODEL + d0) = cv.u;
}

// -------- x2 = x_ln + LN2(attn_out); x3b = bf16(LN3(x2)) --------------------
__global__ __launch_bounds__(256)
void ln23_kernel(const float* __restrict__ ao, const float* __restrict__ xln,
                 const float* __restrict__ g2, const float* __restrict__ bb2,
                 const float* __restrict__ g3, const float* __restrict__ bb3,
                 float* __restrict__ x2o, bf16_t* __restrict__ x3b) {
  __shared__ float red[8];
  const int t = blockIdx.x;
  const int d0 = threadIdx.x * 4;
  const int w = threadIdx.x >> 6, lane = threadIdx.x & 63;

  float4 a = *(const float4*)(ao + (size_t)t * DMODEL + d0);
  float s1 = a.x + a.y + a.z + a.w;
  float s2 = a.x*a.x + a.y*a.y + a.z*a.z + a.w*a.w;
#pragma unroll
  for (int o = 32; o >= 1; o >>= 1) { s1 += __shfl_xor(s1, o); s2 += __shfl_xor(s2, o); }
  if (lane == 0) { red[w] = s1; red[4 + w] = s2; }
  __syncthreads();
  s1 = red[0] + red[1] + red[2] + red[3];
  s2 = red[4] + red[5] + red[6] + red[7];
  float mean = s1 * (1.0f / DMODEL);
  float var  = s2 * (1.0f / DMODEL) - mean * mean;
  float inv  = rsqrtf(var + LN_EPS);
  float4 gv = *(const float4*)(g2 + d0);
  float4 bv = *(const float4*)(bb2 + d0);
  float4 xv = *(const float4*)(xln + (size_t)t * DMODEL + d0);
  float y0 = xv.x + (a.x - mean) * inv * gv.x + bv.x;
  float y1 = xv.y + (a.y - mean) * inv * gv.y + bv.y;
  float y2 = xv.z + (a.z - mean) * inv * gv.z + bv.z;
  float y3 = xv.w + (a.w - mean) * inv * gv.w + bv.w;
  *(float4*)(x2o + (size_t)t * DMODEL + d0) = make_float4(y0, y1, y2, y3);

  // second LN (LN3) on x2
  float t1 = y0 + y1 + y2 + y3;
  float t2 = y0*y0 + y1*y1 + y2*y2 + y3*y3;
#pragma unroll
  for (int o = 32; o >= 1; o >>= 1) { t1 += __shfl_xor(t1, o); t2 += __shfl_xor(t2, o); }
  __syncthreads();                         // all phase-1 reads of red[] done
  if (lane == 0) { red[w] = t1; red[4 + w] = t2; }
  __syncthreads();
  t1 = red[0] + red[1] + red[2] + red[3];
  t2 = red[4] + red[5] + red[6] + red[7];
  float mean2 = t1 * (1.0f / DMODEL);
  float var2  = t2 * (1.0f / DMODEL) - mean2 * mean2;
  float inv2  = rsqrtf(var2 + LN_EPS);
  float4 gv3 = *(const float4*)(g3 + d0);
  float4 bv3 = *(const float4*)(bb3 + d0);
  union { ushort4 u; bf16_t b[4]; } cv;
  cv.b[0] = (bf16_t)((y0 - mean2) * inv2 * gv3.x + bv3.x);
  cv.b[1] = (bf16_t)((y1 - mean2) * inv2 * gv3.y + bv3.y);
  cv.b[2] = (bf16_t)((y2 - mean2) * inv2 * gv3.z + bv3.z);
  cv.b[3] = (bf16_t)((y3 - mean2) * inv2 * gv3.w + bv3.w);
  *(ushort4*)(x3b + (size_t)t * DMODEL + d0) = cv.u;
}

// ---------------- generic TN bf16 GEMM: C = A[M,K] @ B[N,K]^T + bias --------
// EPI: 0 = bf16 store, 1 = f32 store, 2 = exact-GELU + bf16, 3 = +res f32
constexpr int EPI_BF16 = 0, EPI_F32 = 1, EPI_GELU = 2, EPI_RES = 3;

template <int EPI>
__global__ __launch_bounds__(256, 2)
void gemm_bt(const bf16_t* __restrict__ A, const bf16_t* __restrict__ B,
             const float* __restrict__ bias, const float* __restrict__ res,
             bf16_t* __restrict__ obf, float* __restrict__ of32,
             int M, int N, int K) {
  __shared__ __attribute__((aligned(16))) bf16_t As[128 * 64];
  __shared__ __attribute__((aligned(16))) bf16_t Bs[128 * 64];
  const int tid = threadIdx.x;
  const int w = tid >> 6, lane = tid & 63;
  const int quad = lane >> 4, l16 = lane & 15;
  const int m0 = blockIdx.x * 128, n0 = blockIdx.y * 128;
  const int wm = (w >> 1) * 64, wn = (w & 1) * 64;
  const size_t Kz = (size_t)K;

  f32x4 acc[4][4] = {};

  const bf16_t* Ag = A + (size_t)(m0 + w * 32 + (lane >> 3)) * Kz + (lane & 7) * 8;
  const bf16_t* Bg = B + (size_t)(n0 + w * 32 + (lane >> 3)) * Kz + (lane & 7) * 8;
  bf16_t* Asw = &As[(w * 32) * 64];
  bf16_t* Bsw = &Bs[(w * 32) * 64];

  for (int k0 = 0; k0 < K; k0 += 64) {
#pragma unroll
    for (int i = 0; i < 4; ++i) {
      gload_lds16(Ag + (size_t)i * 8 * Kz + k0, Asw + i * 8 * 64);
      gload_lds16(Bg + (size_t)i * 8 * Kz + k0, Bsw + i * 8 * 64);
    }
    __syncthreads();
#pragma unroll
    for (int kc = 0; kc < 2; ++kc) {
      bf16x8 af[4], bfr[4];
#pragma unroll
      for (int i = 0; i < 4; ++i) {
        af[i]  = *(const bf16x8*)&As[(wm + i * 16 + l16) * 64 + kc * 32 + quad * 8];
        bfr[i] = *(const bf16x8*)&Bs[(wn + i * 16 + l16) * 64 + kc * 32 + quad * 8];
      }
#pragma unroll
      for (int mi = 0; mi < 4; ++mi)
#pragma unroll
        for (int ni = 0; ni < 4; ++ni)
          acc[mi][ni] = MFMA_BF16(af[mi], bfr[ni], acc[mi][ni]);
    }
    __syncthreads();
  }

#pragma unroll
  for (int ni = 0; ni < 4; ++ni) {
    const int col = n0 + wn + ni * 16 + l16;
    const float bv = bias[col];
#pragma unroll
    for (int mi = 0; mi < 4; ++mi) {
#pragma unroll
      for (int r = 0; r < 4; ++r) {
        const int row = m0 + wm + mi * 16 + quad * 4 + r;
        float v = acc[mi][ni][r] + bv;
        if constexpr (EPI == EPI_GELU)
          v = 0.5f * v * (1.0f + erff(v * 0.70710678118654752f));
        if constexpr (EPI == EPI_RES)
          v += res[(size_t)row * N + col];
        if constexpr (EPI == EPI_BF16 || EPI == EPI_GELU)
          obf[(size_t)row * N + col] = (bf16_t)v;
        else
          of32[(size_t)row * N + col] = v;
      }
    }
  }
}

// ---------------- V transpose: qkv V-part [tok][h*64+d] -> Vt[bh][d][s] -----
__global__ __launch_bounds__(256)
void vtrans_kernel(const bf16_t* __restrict__ qkv, bf16_t* __restrict__ Vt) {
  __shared__ bf16_t tile[64][72];
  const int bh = blockIdx.y;
  const int b = bh >> 4, h = bh & 15;
  const int s0 = blockIdx.x * 64;
  const int c = threadIdx.x & 63, rb = threadIdx.x >> 6;
#pragma unroll
  for (int i = 0; i < 16; ++i) {
    int r = i * 4 + rb;                       // s-local
    tile[r][c] = qkv[(size_t)(b * SEQ + s0 + r) * 3072 + 2048 + h * 64 + c];
  }
  __syncthreads();
#pragma unroll
  for (int i = 0; i < 16; ++i) {
    int r = i * 4 + rb;                       // d index
    Vt[((size_t)bh * 64 + r) * SEQ + s0 + c] = tile[c][r];
  }
}

// ---------------- flash attention, causal + key pad mask --------------------
// R2: one wave (64 threads) per 32 q-rows. No __syncthreads anywhere.
// K / V^T fragments read directly from global (L1/L2-resident, 16x64B
// segments per wave-load). LDS only holds the wave-local P matrices.
// Grid: (64 strips, 32 bh); sid = 63-blockIdx.x so longest strips launch
// first (LPT-style balance of the causal triangle).
__global__ __launch_bounds__(64)
void attn_kernel(const bf16_t* __restrict__ qkv, const bf16_t* __restrict__ Vt,
                 const int* __restrict__ tokens, bf16_t* __restrict__ attnb) {
  __shared__ __attribute__((aligned(16))) bf16_t Ps[2][16 * 136];  // P for mi=0,1

  const int lane = threadIdx.x;
  const int quad = lane >> 4, l16 = lane & 15;
  const int sid = 63 - (int)blockIdx.x;      // longest-first
  const int bh = blockIdx.y;
  const int b = bh >> 4, h = bh & 15;
  const int qbase = sid * 32;
  const int nkt = (sid >> 2) + 1;            // # of 128-key tiles (causal)

  // Q fragments in registers (A-layout: m=lane&15, k=quad*8+j)
  bf16x8 qf[2][2];
#pragma unroll
  for (int mi = 0; mi < 2; ++mi) {
    const size_t trow = (size_t)(b * SEQ + qbase + mi * 16 + l16) * 3072 + h * 64;
#pragma unroll
    for (int kc = 0; kc < 2; ++kc)
      qf[mi][kc] = *(const bf16x8*)(qkv + trow + kc * 32 + quad * 8);
  }

  f32x4 oacc[2][4] = {};
  float mst[2][4], lst[2][4];
#pragma unroll
  for (int mi = 0; mi < 2; ++mi)
#pragma unroll
    for (int r = 0; r < 4; ++r) { mst[mi][r] = -1e30f; lst[mi][r] = 0.0f; }

  const bf16_t* Kbase = qkv + (size_t)b * SEQ * 3072 + 1024 + h * 64;
  const bf16_t* Vbase = Vt + (size_t)bh * 64 * SEQ;
  const int*    tokb  = tokens + b * SEQ;

  for (int kt = 0; kt < nkt; ++kt) {
    const int k0 = kt * 128;
    const bool diag = (kt == nkt - 1);

    float padneg[8];
#pragma unroll
    for (int ni = 0; ni < 8; ++ni)
      padneg[ni] = (tokb[k0 + ni * 16 + l16] == 0) ? NEGV : 0.0f;

    // --- scores for both 16-row sub-tiles, K fragments loaded once ---
    f32x4 sc[2][8] = {};
#pragma unroll
    for (int kc = 0; kc < 2; ++kc)
#pragma unroll
      for (int ni = 0; ni < 8; ++ni) {
        bf16x8 kf = *(const bf16x8*)(Kbase + (size_t)(k0 + ni * 16 + l16) * 3072
                                     + kc * 32 + quad * 8);
        sc[0][ni] = MFMA_BF16(qf[0][kc], kf, sc[0][ni]);
        sc[1][ni] = MFMA_BF16(qf[1][kc], kf, sc[1][ni]);
      }

    // --- scale + masks + online softmax per sub-tile; P -> wave-local LDS ---
#pragma unroll
    for (int mi = 0; mi < 2; ++mi) {
#pragma unroll
      for (int ni = 0; ni < 8; ++ni) {
        const int key = k0 + ni * 16 + l16;
#pragma unroll
        for (int r = 0; r < 4; ++r) {
          float v = sc[mi][ni][r] * 0.125f + padneg[ni];
          if (diag) {
            int qg = qbase + mi * 16 + quad * 4 + r;
            if (key > qg) v += NEGV;
          }
          sc[mi][ni][r] = v;
        }
      }
      float alpha[4], rs[4];
#pragma unroll
      for (int r = 0; r < 4; ++r) {
        float m = sc[mi][0][r];
#pragma unroll
        for (int ni = 1; ni < 8; ++ni) m = fmaxf(m, sc[mi][ni][r]);
        m = fmaxf(m, __shfl_xor(m, 1));
        m = fmaxf(m, __shfl_xor(m, 2));
        m = fmaxf(m, __shfl_xor(m, 4));
        m = fmaxf(m, __shfl_xor(m, 8));
        float nm = fmaxf(mst[mi][r], m);
        alpha[r] = __expf(mst[mi][r] - nm);
        mst[mi][r] = nm;
        rs[r] = 0.0f;
      }
#pragma unroll
      for (int ni = 0; ni < 8; ++ni)
#pragma unroll
        for (int r = 0; r < 4; ++r) {
          float p = __expf(sc[mi][ni][r] - mst[mi][r]);
          rs[r] += p;
          Ps[mi][(quad * 4 + r) * 136 + ni * 16 + l16] = (bf16_t)p;
        }
#pragma unroll
      for (int r = 0; r < 4; ++r) {
        rs[r] += __shfl_xor(rs[r], 1);
        rs[r] += __shfl_xor(rs[r], 2);
        rs[r] += __shfl_xor(rs[r], 4);
        rs[r] += __shfl_xor(rs[r], 8);
        lst[mi][r] = lst[mi][r] * alpha[r] + rs[r];
      }
#pragma unroll
      for (int nd = 0; nd < 4; ++nd)
#pragma unroll
        for (int r = 0; r < 4; ++r) oacc[mi][nd][r] *= alpha[r];
    }

    // --- P @ V, V fragments loaded once and shared by both sub-tiles ---
    // (wave-local LDS: DS ops are in-order per wave, no barrier needed)
#pragma unroll
    for (int kc2 = 0; kc2 < 4; ++kc2) {
      bf16x8 pf0 = *(const bf16x8*)&Ps[0][l16 * 136 + kc2 * 32 + quad * 8];
      bf16x8 pf1 = *(const bf16x8*)&Ps[1][l16 * 136 + kc2 * 32 + quad * 8];
#pragma unroll
      for (int nd = 0; nd < 4; ++nd) {
        bf16x8 vf = *(const bf16x8*)(Vbase + (size_t)(nd * 16 + l16) * SEQ
                                     + k0 + kc2 * 32 + quad * 8);
        oacc[0][nd] = MFMA_BF16(pf0, vf, oacc[0][nd]);
        oacc[1][nd] = MFMA_BF16(pf1, vf, oacc[1][nd]);
      }
    }
  }

  // normalize and write attn output [tok][h*64+d] bf16
#pragma unroll
  for (int mi = 0; mi < 2; ++mi)
#pragma unroll
    for (int r = 0; r < 4; ++r) {
      const int q = qbase + mi * 16 + quad * 4 + r;
      const float invl = 1.0f / lst[mi][r];
#pragma unroll
      for (int nd = 0; nd < 4; ++nd)
        attnb[(size_t)(b * SEQ + q) * DMODEL + h * 64 + nd * 16 + l16] =
            (bf16_t)(oacc[mi][nd][r] * invl);
    }
}

// ---------------------------------------------------------------------------
extern "C" void kernel_launch(void* const* d_in, const int* in_sizes, int n_in,
                              void* d_out, int out_size, void* d_ws, size_t ws_size,
                              hipStream_t stream) {
  const int*   tokens = (const int*)d_in[0];
  const float* emb    = (const float*)d_in[1];
  const float* pos    = (const float*)d_in[2];
  const float* ln1g   = (const float*)d_in[3];
  const float* ln1b   = (const float*)d_in[4];
  const float* ln2g   = (const float*)d_in[5];
  const float* ln2b   = (const float*)d_in[6];
  const float* ln3g   = (const float*)d_in[7];
  const float* ln3b   = (const float*)d_in[8];
  const float* Wq     = (const float*)d_in[9];
  const float* bq     = (const float*)d_in[10];
  const float* Wk     = (const float*)d_in[11];
  const float* bk     = (const float*)d_in[12];
  const float* Wv     = (const float*)d_in[13];
  const float* bv     = (const float*)d_in[14];
  const float* Wo     = (const float*)d_in[15];
  const float* bo     = (const float*)d_in[16];
  const float* W1     = (const float*)d_in[17];
  const float* b1     = (const float*)d_in[18];
  const float* W2     = (const float*)d_in[19];
  const float* b2     = (const float*)d_in[20];
  float* out = (float*)d_out;

  char* p = (char*)d_ws;
  auto alloc = [&](size_t bytes) {
    char* q = p; p += (bytes + 255) & ~(size_t)255; return q;
  };
  float*  x_ln   = (float*)alloc((size_t)NTOK * DMODEL * 4);
  bf16_t* x_lnb  = (bf16_t*)alloc((size_t)NTOK * DMODEL * 2);
  bf16_t* WqkvT  = (bf16_t*)alloc((size_t)3072 * 1024 * 2);
  float*  bqkv   = (float*)alloc(3072 * 4);
  bf16_t* WoT    = (bf16_t*)alloc((size_t)1024 * 1024 * 2);
  bf16_t* W1T    = (bf16_t*)alloc((size_t)4096 * 1024 * 2);
  bf16_t* W2T    = (bf16_t*)alloc((size_t)1024 * 4096 * 2);
  bf16_t* qkvb   = (bf16_t*)alloc((size_t)NTOK * 3072 * 2);
  bf16_t* Vtb    = (bf16_t*)alloc((size_t)32 * 64 * SEQ * 2);
  bf16_t* attnb  = (bf16_t*)alloc((size_t)NTOK * DMODEL * 2);
  float*  attn_o = (float*)alloc((size_t)NTOK * DMODEL * 4);
  float*  x2     = (float*)alloc((size_t)NTOK * DMODEL * 4);
  bf16_t* x3b    = (bf16_t*)alloc((size_t)NTOK * DMODEL * 2);
  bf16_t* hbuf   = (bf16_t*)alloc((size_t)NTOK * 4096 * 2);

  // weight prep (re-done every call; ws is re-poisoned by harness)
  wtrans_kernel<<<dim3(16, 16), 256, 0, stream>>>(Wq, WqkvT,                 1024, 1024);
  wtrans_kernel<<<dim3(16, 16), 256, 0, stream>>>(Wk, WqkvT + 1024ull * 1024, 1024, 1024);
  wtrans_kernel<<<dim3(16, 16), 256, 0, stream>>>(Wv, WqkvT + 2048ull * 1024, 1024, 1024);
  wtrans_kernel<<<dim3(16, 16), 256, 0, stream>>>(Wo, WoT, 1024, 1024);
  wtrans_kernel<<<dim3(64, 16), 256, 0, stream>>>(W1, W1T, 1024, 4096);
  wtrans_kernel<<<dim3(16, 64), 256, 0, stream>>>(W2, W2T, 4096, 1024);
  pack_bias_kernel<<<4, 256, 0, stream>>>(bq, bk, bv, bqkv);

  // embed + LN1
  ln1_kernel<<<NTOK, 256, 0, stream>>>(tokens, emb, pos, ln1g, ln1b, x_ln, x_lnb);

  // QKV projection (packed N=3072)
  gemm_bt<EPI_BF16><<<dim3(32, 24), 256, 0, stream>>>(
      x_lnb, WqkvT, bqkv, nullptr, qkvb, nullptr, NTOK, 3072, 1024);

  // V transpose for PV MFMA
  vtrans_kernel<<<dim3(32, 32), 256, 0, stream>>>(qkvb, Vtb);

  // flash attention (single-wave blocks, longest strips first)
  attn_kernel<<<dim3(64, 32), 64, 0, stream>>>(qkvb, Vtb, tokens, attnb);

  // output projection
  gemm_bt<EPI_F32><<<dim3(32, 8), 256, 0, stream>>>(
      attnb, WoT, bo, nullptr, nullptr, attn_o, NTOK, 1024, 1024);

  // x2 = x_ln + LN2(attn_out);  x3b = bf16(LN3(x2))
  ln23_kernel<<<NTOK, 256, 0, stream>>>(attn_o, x_ln, ln2g, ln2b, ln3g, ln3b, x2, x3b);

  // FFN up + exact GELU
  gemm_bt<EPI_GELU><<<dim3(32, 32), 256, 0, stream>>>(
      x3b, W1T, b1, nullptr, hbuf, nullptr, NTOK, 4096, 1024);

  // FFN down + residual -> out
  gemm_bt<EPI_RES><<<dim3(32, 8), 256, 0, stream>>>(
      hbuf, W2T, b2, x2, nullptr, out, NTOK, 1024, 4096);

  (void)in_sizes; (void)n_in; (void)out_size; (void)ws_size;
}

// Round 3
// 568.973 us; speedup vs baseline: 1.3496x; 1.3496x over previous
//
#include <hip/hip_runtime.h>
#include <cstdint>
#include <cstddef>

// ---------------------------------------------------------------------------
// TransformerEncoderLayer on MI355X (gfx950)
// B=2, S=2048, D_MODEL=1024, 16 heads x 64, VOCAB=32000, PAD=0
// bf16 MFMA for all GEMMs + flash attention; fp32 LN / residual streams.
// R3: attention = R1 multi-wave LDS structure + uniform strip-pairing
//     (17 k-tiles per block, exact) + XOR-swizzled K staging (bank-conflict
//     free fragment reads).
// ---------------------------------------------------------------------------

#define SEQ     2048
#define NTOK    4096          // B*S
#define DMODEL  1024
#define NHEAD   16
#define DHEAD   64
#define NEGV    (-1000000000.0f)
#define LN_EPS  1e-5f

typedef __bf16 bf16_t;
typedef __bf16 bf16x8 __attribute__((ext_vector_type(8)));
typedef float  f32x4  __attribute__((ext_vector_type(4)));

#define MFMA_BF16(a,b,c) __builtin_amdgcn_mfma_f32_16x16x32_bf16((a),(b),(c),0,0,0)

__device__ __forceinline__ void gload_lds16(const void* g, void* l) {
  __builtin_amdgcn_global_load_lds(
      (__attribute__((address_space(1))) void*)(g),
      (__attribute__((address_space(3))) void*)(l), 16, 0, 0);
}

// ---------------- weight transpose+convert: W[K][N] f32 -> WT[N][K] bf16 ----
__global__ __launch_bounds__(256)
void wtrans_kernel(const float* __restrict__ W, bf16_t* __restrict__ WT,
                   int K, int N) {
  __shared__ float tile[64][65];
  const int n0 = blockIdx.x * 64, k0 = blockIdx.y * 64;
  const int c = threadIdx.x & 63, rb = threadIdx.x >> 6;
#pragma unroll
  for (int i = 0; i < 16; ++i) {
    int r = i * 4 + rb;
    tile[r][c] = W[(size_t)(k0 + r) * N + n0 + c];
  }
  __syncthreads();
#pragma unroll
  for (int i = 0; i < 16; ++i) {
    int r = i * 4 + rb;                       // output row (n), col (k)
    WT[(size_t)(n0 + r) * K + k0 + c] = (bf16_t)tile[c][r];
  }
}

__global__ __launch_bounds__(256)
void pack_bias_kernel(const float* __restrict__ bq, const float* __restrict__ bk,
                      const float* __restrict__ bv, float* __restrict__ o) {
  int i = blockIdx.x * 256 + threadIdx.x;
  if (i < 1024) { o[i] = bq[i]; o[1024 + i] = bk[i]; o[2048 + i] = bv[i]; }
}

// ---------------- embed + pos + LN1 -> x_ln f32, x_ln bf16 ------------------
__global__ __launch_bounds__(256)
void ln1_kernel(const int* __restrict__ tokens, const float* __restrict__ emb,
                const float* __restrict__ pos, const float* __restrict__ g,
                const float* __restrict__ bb, float* __restrict__ xln,
                bf16_t* __restrict__ xlnb) {
  __shared__ float red[8];
  const int t = blockIdx.x;
  const int s = t & (SEQ - 1);
  const int tok = tokens[t];
  const int d0 = threadIdx.x * 4;
  const int w = threadIdx.x >> 6, lane = threadIdx.x & 63;

  float4 e  = *(const float4*)(emb + (size_t)tok * DMODEL + d0);
  float4 pp = *(const float4*)(pos + (size_t)s   * DMODEL + d0);
  float x0 = e.x + pp.x, x1 = e.y + pp.y, x2v = e.z + pp.z, x3v = e.w + pp.w;
  float s1 = x0 + x1 + x2v + x3v;
  float s2 = x0*x0 + x1*x1 + x2v*x2v + x3v*x3v;
#pragma unroll
  for (int o = 32; o >= 1; o >>= 1) { s1 += __shfl_xor(s1, o); s2 += __shfl_xor(s2, o); }
  if (lane == 0) { red[w] = s1; red[4 + w] = s2; }
  __syncthreads();
  s1 = red[0] + red[1] + red[2] + red[3];
  s2 = red[4] + red[5] + red[6] + red[7];
  float mean = s1 * (1.0f / DMODEL);
  float var  = s2 * (1.0f / DMODEL) - mean * mean;
  float inv  = rsqrtf(var + LN_EPS);
  float4 gv = *(const float4*)(g + d0);
  float4 bv = *(const float4*)(bb + d0);
  float y0 = (x0  - mean) * inv * gv.x + bv.x;
  float y1 = (x1  - mean) * inv * gv.y + bv.y;
  float y2 = (x2v - mean) * inv * gv.z + bv.z;
  float y3 = (x3v - mean) * inv * gv.w + bv.w;
  *(float4*)(xln + (size_t)t * DMODEL + d0) = make_float4(y0, y1, y2, y3);
  union { ushort4 u; bf16_t b[4]; } cv;
  cv.b[0] = (bf16_t)y0; cv.b[1] = (bf16_t)y1; cv.b[2] = (bf16_t)y2; cv.b[3] = (bf16_t)y3;
  *(ushort4*)(xlnb + (size_t)t * DMODEL + d0) = cv.u;
}

// -------- x2 = x_ln + LN2(attn_out); x3b = bf16(LN3(x2)) --------------------
__global__ __launch_bounds__(256)
void ln23_kernel(const float* __restrict__ ao, const float* __restrict__ xln,
                 const float* __restrict__ g2, const float* __restrict__ bb2,
                 const float* __restrict__ g3, const float* __restrict__ bb3,
                 float* __restrict__ x2o, bf16_t* __restrict__ x3b) {
  __shared__ float red[8];
  const int t = blockIdx.x;
  const int d0 = threadIdx.x * 4;
  const int w = threadIdx.x >> 6, lane = threadIdx.x & 63;

  float4 a = *(const float4*)(ao + (size_t)t * DMODEL + d0);
  float s1 = a.x + a.y + a.z + a.w;
  float s2 = a.x*a.x + a.y*a.y + a.z*a.z + a.w*a.w;
#pragma unroll
  for (int o = 32; o >= 1; o >>= 1) { s1 += __shfl_xor(s1, o); s2 += __shfl_xor(s2, o); }
  if (lane == 0) { red[w] = s1; red[4 + w] = s2; }
  __syncthreads();
  s1 = red[0] + red[1] + red[2] + red[3];
  s2 = red[4] + red[5] + red[6] + red[7];
  float mean = s1 * (1.0f / DMODEL);
  float var  = s2 * (1.0f / DMODEL) - mean * mean;
  float inv  = rsqrtf(var + LN_EPS);
  float4 gv = *(const float4*)(g2 + d0);
  float4 bv = *(const float4*)(bb2 + d0);
  float4 xv = *(const float4*)(xln + (size_t)t * DMODEL + d0);
  float y0 = xv.x + (a.x - mean) * inv * gv.x + bv.x;
  float y1 = xv.y + (a.y - mean) * inv * gv.y + bv.y;
  float y2 = xv.z + (a.z - mean) * inv * gv.z + bv.z;
  float y3 = xv.w + (a.w - mean) * inv * gv.w + bv.w;
  *(float4*)(x2o + (size_t)t * DMODEL + d0) = make_float4(y0, y1, y2, y3);

  // second LN (LN3) on x2
  float t1 = y0 + y1 + y2 + y3;
  float t2 = y0*y0 + y1*y1 + y2*y2 + y3*y3;
#pragma unroll
  for (int o = 32; o >= 1; o >>= 1) { t1 += __shfl_xor(t1, o); t2 += __shfl_xor(t2, o); }
  __syncthreads();                         // all phase-1 reads of red[] done
  if (lane == 0) { red[w] = t1; red[4 + w] = t2; }
  __syncthreads();
  t1 = red[0] + red[1] + red[2] + red[3];
  t2 = red[4] + red[5] + red[6] + red[7];
  float mean2 = t1 * (1.0f / DMODEL);
  float var2  = t2 * (1.0f / DMODEL) - mean2 * mean2;
  float inv2  = rsqrtf(var2 + LN_EPS);
  float4 gv3 = *(const float4*)(g3 + d0);
  float4 bv3 = *(const float4*)(bb3 + d0);
  union { ushort4 u; bf16_t b[4]; } cv;
  cv.b[0] = (bf16_t)((y0 - mean2) * inv2 * gv3.x + bv3.x);
  cv.b[1] = (bf16_t)((y1 - mean2) * inv2 * gv3.y + bv3.y);
  cv.b[2] = (bf16_t)((y2 - mean2) * inv2 * gv3.z + bv3.z);
  cv.b[3] = (bf16_t)((y3 - mean2) * inv2 * gv3.w + bv3.w);
  *(ushort4*)(x3b + (size_t)t * DMODEL + d0) = cv.u;
}

// ---------------- generic TN bf16 GEMM: C = A[M,K] @ B[N,K]^T + bias --------
// EPI: 0 = bf16 store, 1 = f32 store, 2 = exact-GELU + bf16, 3 = +res f32
constexpr int EPI_BF16 = 0, EPI_F32 = 1, EPI_GELU = 2, EPI_RES = 3;

template <int EPI>
__global__ __launch_bounds__(256, 2)
void gemm_bt(const bf16_t* __restrict__ A, const bf16_t* __restrict__ B,
             const float* __restrict__ bias, const float* __restrict__ res,
             bf16_t* __restrict__ obf, float* __restrict__ of32,
             int M, int N, int K) {
  __shared__ __attribute__((aligned(16))) bf16_t As[128 * 64];
  __shared__ __attribute__((aligned(16))) bf16_t Bs[128 * 64];
  const int tid = threadIdx.x;
  const int w = tid >> 6, lane = tid & 63;
  const int quad = lane >> 4, l16 = lane & 15;
  const int m0 = blockIdx.x * 128, n0 = blockIdx.y * 128;
  const int wm = (w >> 1) * 64, wn = (w & 1) * 64;
  const size_t Kz = (size_t)K;

  f32x4 acc[4][4] = {};

  const bf16_t* Ag = A + (size_t)(m0 + w * 32 + (lane >> 3)) * Kz + (lane & 7) * 8;
  const bf16_t* Bg = B + (size_t)(n0 + w * 32 + (lane >> 3)) * Kz + (lane & 7) * 8;
  bf16_t* Asw = &As[(w * 32) * 64];
  bf16_t* Bsw = &Bs[(w * 32) * 64];

  for (int k0 = 0; k0 < K; k0 += 64) {
#pragma unroll
    for (int i = 0; i < 4; ++i) {
      gload_lds16(Ag + (size_t)i * 8 * Kz + k0, Asw + i * 8 * 64);
      gload_lds16(Bg + (size_t)i * 8 * Kz + k0, Bsw + i * 8 * 64);
    }
    __syncthreads();
#pragma unroll
    for (int kc = 0; kc < 2; ++kc) {
      bf16x8 af[4], bfr[4];
#pragma unroll
      for (int i = 0; i < 4; ++i) {
        af[i]  = *(const bf16x8*)&As[(wm + i * 16 + l16) * 64 + kc * 32 + quad * 8];
        bfr[i] = *(const bf16x8*)&Bs[(wn + i * 16 + l16) * 64 + kc * 32 + quad * 8];
      }
#pragma unroll
      for (int mi = 0; mi < 4; ++mi)
#pragma unroll
        for (int ni = 0; ni < 4; ++ni)
          acc[mi][ni] = MFMA_BF16(af[mi], bfr[ni], acc[mi][ni]);
    }
    __syncthreads();
  }

#pragma unroll
  for (int ni = 0; ni < 4; ++ni) {
    const int col = n0 + wn + ni * 16 + l16;
    const float bv = bias[col];
#pragma unroll
    for (int mi = 0; mi < 4; ++mi) {
#pragma unroll
      for (int r = 0; r < 4; ++r) {
        const int row = m0 + wm + mi * 16 + quad * 4 + r;
        float v = acc[mi][ni][r] + bv;
        if constexpr (EPI == EPI_GELU)
          v = 0.5f * v * (1.0f + erff(v * 0.70710678118654752f));
        if constexpr (EPI == EPI_RES)
          v += res[(size_t)row * N + col];
        if constexpr (EPI == EPI_BF16 || EPI == EPI_GELU)
          obf[(size_t)row * N + col] = (bf16_t)v;
        else
          of32[(size_t)row * N + col] = v;
      }
    }
  }
}

// ---------------- V transpose: qkv V-part [tok][h*64+d] -> Vt[bh][d][s] -----
__global__ __launch_bounds__(256)
void vtrans_kernel(const bf16_t* __restrict__ qkv, bf16_t* __restrict__ Vt) {
  __shared__ bf16_t tile[64][72];
  const int bh = blockIdx.y;
  const int b = bh >> 4, h = bh & 15;
  const int s0 = blockIdx.x * 64;
  const int c = threadIdx.x & 63, rb = threadIdx.x >> 6;
#pragma unroll
  for (int i = 0; i < 16; ++i) {
    int r = i * 4 + rb;                       // s-local
    tile[r][c] = qkv[(size_t)(b * SEQ + s0 + r) * 3072 + 2048 + h * 64 + c];
  }
  __syncthreads();
#pragma unroll
  for (int i = 0; i < 16; ++i) {
    int r = i * 4 + rb;                       // d index
    Vt[((size_t)bh * 64 + r) * SEQ + s0 + c] = tile[c][r];
  }
}

// ---------------- flash attention, causal + key pad mask --------------------
// R3: block = (pair p, bh), 256 threads = 4 waves. Processes q-strips p and
// 31-p (64 rows each, 16 rows/wave). Tile count = 17 for EVERY p (exact
// uniformity: (p>>1) + ((31-p)>>1) = 15). K staged via global_load_lds with
// XOR-swizzled chunks so fragment reads are bank-conflict-free; V^T staged
// manually with padded stride 136.
__global__ __launch_bounds__(256, 2)
void attn_kernel(const bf16_t* __restrict__ qkv, const bf16_t* __restrict__ Vt,
                 const int* __restrict__ tokens, bf16_t* __restrict__ attnb) {
  __shared__ __attribute__((aligned(16))) bf16_t Ks[128 * 64];     // [key][d] swizzled
  __shared__ __attribute__((aligned(16))) bf16_t Vts[64 * 136];    // [d][key] padded
  __shared__ __attribute__((aligned(16))) bf16_t Ps[4][16 * 136];  // per-wave P

  const int tid = threadIdx.x;
  const int w = tid >> 6, lane = tid & 63;
  const int quad = lane >> 4, l16 = lane & 15;
  const int pr = blockIdx.x;                 // 0..15
  const int bh = blockIdx.y;
  const int b = bh >> 4, h = bh & 15;

  const bf16_t* Kbase = qkv + (size_t)b * SEQ * 3072 + 1024 + h * 64;
  const bf16_t* Vbase = Vt + (size_t)bh * 64 * SEQ;
  const int*    tokb  = tokens + b * SEQ;
  bf16_t* Pw = Ps[w];

  // staging swizzle: lane loads global chunk (lane&7)^((lane>>3)&7) of its row
  const int sw_chunk = (lane & 7) ^ ((lane >> 3) & 7);
  const int xr = l16 & 7;                    // row-dependent read swizzle

  for (int half = 0; half < 2; ++half) {
    const int strip = half ? (31 - pr) : pr; // 64-row q-strip index
    const int ntiles = (strip >> 1) + 1;
    const int qrow0 = strip * 64 + w * 16;   // this wave's 16 q-rows

    // Q fragments (A-layout: m=l16, k=quad*8+j)
    bf16x8 qf[2];
    {
      const size_t trow = (size_t)(b * SEQ + qrow0 + l16) * 3072 + h * 64;
      qf[0] = *(const bf16x8*)(qkv + trow + quad * 8);
      qf[1] = *(const bf16x8*)(qkv + trow + 32 + quad * 8);
    }

    f32x4 oacc[4] = {};
    float mst[4], lst[4];
#pragma unroll
    for (int r = 0; r < 4; ++r) { mst[r] = -1e30f; lst[r] = 0.0f; }

    for (int kt = 0; kt < ntiles; ++kt) {
      const int k0 = kt * 128;
      // stage K rows [w*32, w*32+32), swizzled chunks, 16B/lane DMA
      {
        const bf16_t* Kg = Kbase + (size_t)(k0 + w * 32 + (lane >> 3)) * 3072
                           + sw_chunk * 8;
        bf16_t* Kl = &Ks[(w * 32) * 64];
#pragma unroll
        for (int i = 0; i < 4; ++i)
          gload_lds16(Kg + (size_t)i * 8 * 3072, Kl + i * 8 * 64);
      }
      // stage V^T tile (padded stride 136)
#pragma unroll
      for (int i = 0; i < 4; ++i) {
        int idx = i * 256 + tid;
        int d = idx >> 4, c = idx & 15;
        uint4 v = *(const uint4*)(Vbase + (size_t)d * SEQ + k0 + c * 8);
        *(uint4*)&Vts[d * 136 + c * 8] = v;
      }
      __syncthreads();

      float padneg[8];
#pragma unroll
      for (int ni = 0; ni < 8; ++ni)
        padneg[ni] = (tokb[k0 + ni * 16 + l16] == 0) ? NEGV : 0.0f;

      const bool diag = (kt == ntiles - 1);

      // --- scores (swizzled kf reads: chunk (kc*4+quad)^xr of row) ---
      f32x4 sc[8] = {};
#pragma unroll
      for (int kc = 0; kc < 2; ++kc)
#pragma unroll
        for (int ni = 0; ni < 8; ++ni) {
          bf16x8 kf = *(const bf16x8*)&Ks[(ni * 16 + l16) * 64
                                          + ((kc * 4 + quad) ^ xr) * 8];
          sc[ni] = MFMA_BF16(qf[kc], kf, sc[ni]);
        }

      // --- scale + masks ---
#pragma unroll
      for (int ni = 0; ni < 8; ++ni) {
        const int key = k0 + ni * 16 + l16;
#pragma unroll
        for (int r = 0; r < 4; ++r) {
          float v = sc[ni][r] * 0.125f + padneg[ni];
          if (diag) {
            int qg = qrow0 + quad * 4 + r;
            if (key > qg) v += NEGV;
          }
          sc[ni][r] = v;
        }
      }

      // --- online softmax (rows = regs) ---
      float alpha[4], rs[4];
#pragma unroll
      for (int r = 0; r < 4; ++r) {
        float m = sc[0][r];
#pragma unroll
        for (int ni = 1; ni < 8; ++ni) m = fmaxf(m, sc[ni][r]);
        m = fmaxf(m, __shfl_xor(m, 1));
        m = fmaxf(m, __shfl_xor(m, 2));
        m = fmaxf(m, __shfl_xor(m, 4));
        m = fmaxf(m, __shfl_xor(m, 8));
        float nm = fmaxf(mst[r], m);
        alpha[r] = __expf(mst[r] - nm);
        mst[r] = nm;
        rs[r] = 0.0f;
      }
#pragma unroll
      for (int ni = 0; ni < 8; ++ni)
#pragma unroll
        for (int r = 0; r < 4; ++r) {
          float p = __expf(sc[ni][r] - mst[r]);
          rs[r] += p;
          Pw[(quad * 4 + r) * 136 + ni * 16 + l16] = (bf16_t)p;
        }
#pragma unroll
      for (int r = 0; r < 4; ++r) {
        rs[r] += __shfl_xor(rs[r], 1);
        rs[r] += __shfl_xor(rs[r], 2);
        rs[r] += __shfl_xor(rs[r], 4);
        rs[r] += __shfl_xor(rs[r], 8);
        lst[r] = lst[r] * alpha[r] + rs[r];
      }
#pragma unroll
      for (int nd = 0; nd < 4; ++nd)
#pragma unroll
        for (int r = 0; r < 4; ++r) oacc[nd][r] *= alpha[r];

      // --- P @ V (P wave-local; DS in-order per wave) ---
#pragma unroll
      for (int kc2 = 0; kc2 < 4; ++kc2) {
        bf16x8 pf = *(const bf16x8*)&Pw[l16 * 136 + kc2 * 32 + quad * 8];
#pragma unroll
        for (int nd = 0; nd < 4; ++nd) {
          bf16x8 vf = *(const bf16x8*)&Vts[(nd * 16 + l16) * 136
                                           + kc2 * 32 + quad * 8];
          oacc[nd] = MFMA_BF16(pf, vf, oacc[nd]);
        }
      }
      __syncthreads();
    }

    // normalize and write this strip's output
#pragma unroll
    for (int r = 0; r < 4; ++r) {
      const int q = qrow0 + quad * 4 + r;
      const float invl = 1.0f / lst[r];
#pragma unroll
      for (int nd = 0; nd < 4; ++nd)
        attnb[(size_t)(b * SEQ + q) * DMODEL + h * 64 + nd * 16 + l16] =
            (bf16_t)(oacc[nd][r] * invl);
    }
  }
}

// ---------------------------------------------------------------------------
extern "C" void kernel_launch(void* const* d_in, const int* in_sizes, int n_in,
                              void* d_out, int out_size, void* d_ws, size_t ws_size,
                              hipStream_t stream) {
  const int*   tokens = (const int*)d_in[0];
  const float* emb    = (const float*)d_in[1];
  const float* pos    = (const float*)d_in[2];
  const float* ln1g   = (const float*)d_in[3];
  const float* ln1b   = (const float*)d_in[4];
  const float* ln2g   = (const float*)d_in[5];
  const float* ln2b   = (const float*)d_in[6];
  const float* ln3g   = (const float*)d_in[7];
  const float* ln3b   = (const float*)d_in[8];
  const float* Wq     = (const float*)d_in[9];
  const float* bq     = (const float*)d_in[10];
  const float* Wk     = (const float*)d_in[11];
  const float* bk     = (const float*)d_in[12];
  const float* Wv     = (const float*)d_in[13];
  const float* bv     = (const float*)d_in[14];
  const float* Wo     = (const float*)d_in[15];
  const float* bo     = (const float*)d_in[16];
  const float* W1     = (const float*)d_in[17];
  const float* b1     = (const float*)d_in[18];
  const float* W2     = (const float*)d_in[19];
  const float* b2     = (const float*)d_in[20];
  float* out = (float*)d_out;

  char* p = (char*)d_ws;
  auto alloc = [&](size_t bytes) {
    char* q = p; p += (bytes + 255) & ~(size_t)255; return q;
  };
  float*  x_ln   = (float*)alloc((size_t)NTOK * DMODEL * 4);
  bf16_t* x_lnb  = (bf16_t*)alloc((size_t)NTOK * DMODEL * 2);
  bf16_t* WqkvT  = (bf16_t*)alloc((size_t)3072 * 1024 * 2);
  float*  bqkv   = (float*)alloc(3072 * 4);
  bf16_t* WoT    = (bf16_t*)alloc((size_t)1024 * 1024 * 2);
  bf16_t* W1T    = (bf16_t*)alloc((size_t)4096 * 1024 * 2);
  bf16_t* W2T    = (bf16_t*)alloc((size_t)1024 * 4096 * 2);
  bf16_t* qkvb   = (bf16_t*)alloc((size_t)NTOK * 3072 * 2);
  bf16_t* Vtb    = (bf16_t*)alloc((size_t)32 * 64 * SEQ * 2);
  bf16_t* attnb  = (bf16_t*)alloc((size_t)NTOK * DMODEL * 2);
  float*  attn_o = (float*)alloc((size_t)NTOK * DMODEL * 4);
  float*  x2     = (float*)alloc((size_t)NTOK * DMODEL * 4);
  bf16_t* x3b    = (bf16_t*)alloc((size_t)NTOK * DMODEL * 2);
  bf16_t* hbuf   = (bf16_t*)alloc((size_t)NTOK * 4096 * 2);

  // weight prep (re-done every call; ws is re-poisoned by harness)
  wtrans_kernel<<<dim3(16, 16), 256, 0, stream>>>(Wq, WqkvT,                 1024, 1024);
  wtrans_kernel<<<dim3(16, 16), 256, 0, stream>>>(Wk, WqkvT + 1024ull * 1024, 1024, 1024);
  wtrans_kernel<<<dim3(16, 16), 256, 0, stream>>>(Wv, WqkvT + 2048ull * 1024, 1024, 1024);
  wtrans_kernel<<<dim3(16, 16), 256, 0, stream>>>(Wo, WoT, 1024, 1024);
  wtrans_kernel<<<dim3(64, 16), 256, 0, stream>>>(W1, W1T, 1024, 4096);
  wtrans_kernel<<<dim3(16, 64), 256, 0, stream>>>(W2, W2T, 4096, 1024);
  pack_bias_kernel<<<4, 256, 0, stream>>>(bq, bk, bv, bqkv);

  // embed + LN1
  ln1_kernel<<<NTOK, 256, 0, stream>>>(tokens, emb, pos, ln1g, ln1b, x_ln, x_lnb);

  // QKV projection (packed N=3072)
  gemm_bt<EPI_BF16><<<dim3(32, 24), 256, 0, stream>>>(
      x_lnb, WqkvT, bqkv, nullptr, qkvb, nullptr, NTOK, 3072, 1024);

  // V transpose for PV MFMA
  vtrans_kernel<<<dim3(32, 32), 256, 0, stream>>>(qkvb, Vtb);

  // flash attention (paired strips, uniform 17 tiles/block)
  attn_kernel<<<dim3(16, 32), 256, 0, stream>>>(qkvb, Vtb, tokens, attnb);

  // output projection
  gemm_bt<EPI_F32><<<dim3(32, 8), 256, 0, stream>>>(
      attnb, WoT, bo, nullptr, nullptr, attn_o, NTOK, 1024, 1024);

  // x2 = x_ln + LN2(attn_out);  x3b = bf16(LN3(x2))
  ln23_kernel<<<NTOK, 256, 0, stream>>>(attn_o, x_ln, ln2g, ln2b, ln3g, ln3b, x2, x3b);

  // FFN up + exact GELU
  gemm_bt<EPI_GELU><<<dim3(32, 32), 256, 0, stream>>>(
      x3b, W1T, b1, nullptr, hbuf, nullptr, NTOK, 4096, 1024);

  // FFN down + residual -> out
  gemm_bt<EPI_RES><<<dim3(32, 8), 256, 0, stream>>>(
      hbuf, W2T, b2, x2, nullptr, out, NTOK, 1024, 4096);

  (void)in_sizes; (void)n_in; (void)out_size; (void)ws_size;
}

// Round 4
// 559.511 us; speedup vs baseline: 1.3724x; 1.0169x over previous
//
#include <hip/hip_runtime.h>
#include <cstdint>
#include <cstddef>

// ---------------------------------------------------------------------------
// TransformerEncoderLayer on MI355X (gfx950)
// B=2, S=2048, D_MODEL=1024, 16 heads x 64, VOCAB=32000, PAD=0
// bf16 MFMA for all GEMMs + flash attention; fp32 LN / residual streams.
// R4: attention = shuffle-free softmax (fixed shift, -30 mask, l via
//     ones-MFMA), 32 q-rows/wave sharing K/V fragment loads, LPT strip
//     scheduling (longest-first). No cross-lane ops anywhere in the kernel.
// ---------------------------------------------------------------------------

#define SEQ     2048
#define NTOK    4096          // B*S
#define DMODEL  1024
#define NHEAD   16
#define DHEAD   64
#define MASKV   (-30.0f)      // soft mask: exp(-30)~1e-13, exact softmax ratios
#define LN_EPS  1e-5f

typedef __bf16 bf16_t;
typedef __bf16 bf16x8 __attribute__((ext_vector_type(8)));
typedef float  f32x4  __attribute__((ext_vector_type(4)));

#define MFMA_BF16(a,b,c) __builtin_amdgcn_mfma_f32_16x16x32_bf16((a),(b),(c),0,0,0)

__device__ __forceinline__ void gload_lds16(const void* g, void* l) {
  __builtin_amdgcn_global_load_lds(
      (__attribute__((address_space(1))) void*)(g),
      (__attribute__((address_space(3))) void*)(l), 16, 0, 0);
}

// ---------------- weight transpose+convert: W[K][N] f32 -> WT[N][K] bf16 ----
__global__ __launch_bounds__(256)
void wtrans_kernel(const float* __restrict__ W, bf16_t* __restrict__ WT,
                   int K, int N) {
  __shared__ float tile[64][65];
  const int n0 = blockIdx.x * 64, k0 = blockIdx.y * 64;
  const int c = threadIdx.x & 63, rb = threadIdx.x >> 6;
#pragma unroll
  for (int i = 0; i < 16; ++i) {
    int r = i * 4 + rb;
    tile[r][c] = W[(size_t)(k0 + r) * N + n0 + c];
  }
  __syncthreads();
#pragma unroll
  for (int i = 0; i < 16; ++i) {
    int r = i * 4 + rb;                       // output row (n), col (k)
    WT[(size_t)(n0 + r) * K + k0 + c] = (bf16_t)tile[c][r];
  }
}

__global__ __launch_bounds__(256)
void pack_bias_kernel(const float* __restrict__ bq, const float* __restrict__ bk,
                      const float* __restrict__ bv, float* __restrict__ o) {
  int i = blockIdx.x * 256 + threadIdx.x;
  if (i < 1024) { o[i] = bq[i]; o[1024 + i] = bk[i]; o[2048 + i] = bv[i]; }
}

// ---------------- embed + pos + LN1 -> x_ln f32, x_ln bf16 ------------------
__global__ __launch_bounds__(256)
void ln1_kernel(const int* __restrict__ tokens, const float* __restrict__ emb,
                const float* __restrict__ pos, const float* __restrict__ g,
                const float* __restrict__ bb, float* __restrict__ xln,
                bf16_t* __restrict__ xlnb) {
  __shared__ float red[8];
  const int t = blockIdx.x;
  const int s = t & (SEQ - 1);
  const int tok = tokens[t];
  const int d0 = threadIdx.x * 4;
  const int w = threadIdx.x >> 6, lane = threadIdx.x & 63;

  float4 e  = *(const float4*)(emb + (size_t)tok * DMODEL + d0);
  float4 pp = *(const float4*)(pos + (size_t)s   * DMODEL + d0);
  float x0 = e.x + pp.x, x1 = e.y + pp.y, x2v = e.z + pp.z, x3v = e.w + pp.w;
  float s1 = x0 + x1 + x2v + x3v;
  float s2 = x0*x0 + x1*x1 + x2v*x2v + x3v*x3v;
#pragma unroll
  for (int o = 32; o >= 1; o >>= 1) { s1 += __shfl_xor(s1, o); s2 += __shfl_xor(s2, o); }
  if (lane == 0) { red[w] = s1; red[4 + w] = s2; }
  __syncthreads();
  s1 = red[0] + red[1] + red[2] + red[3];
  s2 = red[4] + red[5] + red[6] + red[7];
  float mean = s1 * (1.0f / DMODEL);
  float var  = s2 * (1.0f / DMODEL) - mean * mean;
  float inv  = rsqrtf(var + LN_EPS);
  float4 gv = *(const float4*)(g + d0);
  float4 bv = *(const float4*)(bb + d0);
  float y0 = (x0  - mean) * inv * gv.x + bv.x;
  float y1 = (x1  - mean) * inv * gv.y + bv.y;
  float y2 = (x2v - mean) * inv * gv.z + bv.z;
  float y3 = (x3v - mean) * inv * gv.w + bv.w;
  *(float4*)(xln + (size_t)t * DMODEL + d0) = make_float4(y0, y1, y2, y3);
  union { ushort4 u; bf16_t b[4]; } cv;
  cv.b[0] = (bf16_t)y0; cv.b[1] = (bf16_t)y1; cv.b[2] = (bf16_t)y2; cv.b[3] = (bf16_t)y3;
  *(ushort4*)(xlnb + (size_t)t * DMODEL + d0) = cv.u;
}

// -------- x2 = x_ln + LN2(attn_out); x3b = bf16(LN3(x2)) --------------------
__global__ __launch_bounds__(256)
void ln23_kernel(const float* __restrict__ ao, const float* __restrict__ xln,
                 const float* __restrict__ g2, const float* __restrict__ bb2,
                 const float* __restrict__ g3, const float* __restrict__ bb3,
                 float* __restrict__ x2o, bf16_t* __restrict__ x3b) {
  __shared__ float red[8];
  const int t = blockIdx.x;
  const int d0 = threadIdx.x * 4;
  const int w = threadIdx.x >> 6, lane = threadIdx.x & 63;

  float4 a = *(const float4*)(ao + (size_t)t * DMODEL + d0);
  float s1 = a.x + a.y + a.z + a.w;
  float s2 = a.x*a.x + a.y*a.y + a.z*a.z + a.w*a.w;
#pragma unroll
  for (int o = 32; o >= 1; o >>= 1) { s1 += __shfl_xor(s1, o); s2 += __shfl_xor(s2, o); }
  if (lane == 0) { red[w] = s1; red[4 + w] = s2; }
  __syncthreads();
  s1 = red[0] + red[1] + red[2] + red[3];
  s2 = red[4] + red[5] + red[6] + red[7];
  float mean = s1 * (1.0f / DMODEL);
  float var  = s2 * (1.0f / DMODEL) - mean * mean;
  float inv  = rsqrtf(var + LN_EPS);
  float4 gv = *(const float4*)(g2 + d0);
  float4 bv = *(const float4*)(bb2 + d0);
  float4 xv = *(const float4*)(xln + (size_t)t * DMODEL + d0);
  float y0 = xv.x + (a.x - mean) * inv * gv.x + bv.x;
  float y1 = xv.y + (a.y - mean) * inv * gv.y + bv.y;
  float y2 = xv.z + (a.z - mean) * inv * gv.z + bv.z;
  float y3 = xv.w + (a.w - mean) * inv * gv.w + bv.w;
  *(float4*)(x2o + (size_t)t * DMODEL + d0) = make_float4(y0, y1, y2, y3);

  // second LN (LN3) on x2
  float t1 = y0 + y1 + y2 + y3;
  float t2 = y0*y0 + y1*y1 + y2*y2 + y3*y3;
#pragma unroll
  for (int o = 32; o >= 1; o >>= 1) { t1 += __shfl_xor(t1, o); t2 += __shfl_xor(t2, o); }
  __syncthreads();                         // all phase-1 reads of red[] done
  if (lane == 0) { red[w] = t1; red[4 + w] = t2; }
  __syncthreads();
  t1 = red[0] + red[1] + red[2] + red[3];
  t2 = red[4] + red[5] + red[6] + red[7];
  float mean2 = t1 * (1.0f / DMODEL);
  float var2  = t2 * (1.0f / DMODEL) - mean2 * mean2;
  float inv2  = rsqrtf(var2 + LN_EPS);
  float4 gv3 = *(const float4*)(g3 + d0);
  float4 bv3 = *(const float4*)(bb3 + d0);
  union { ushort4 u; bf16_t b[4]; } cv;
  cv.b[0] = (bf16_t)((y0 - mean2) * inv2 * gv3.x + bv3.x);
  cv.b[1] = (bf16_t)((y1 - mean2) * inv2 * gv3.y + bv3.y);
  cv.b[2] = (bf16_t)((y2 - mean2) * inv2 * gv3.z + bv3.z);
  cv.b[3] = (bf16_t)((y3 - mean2) * inv2 * gv3.w + bv3.w);
  *(ushort4*)(x3b + (size_t)t * DMODEL + d0) = cv.u;
}

// ---------------- generic TN bf16 GEMM: C = A[M,K] @ B[N,K]^T + bias --------
// EPI: 0 = bf16 store, 1 = f32 store, 2 = exact-GELU + bf16, 3 = +res f32
constexpr int EPI_BF16 = 0, EPI_F32 = 1, EPI_GELU = 2, EPI_RES = 3;

template <int EPI>
__global__ __launch_bounds__(256, 2)
void gemm_bt(const bf16_t* __restrict__ A, const bf16_t* __restrict__ B,
             const float* __restrict__ bias, const float* __restrict__ res,
             bf16_t* __restrict__ obf, float* __restrict__ of32,
             int M, int N, int K) {
  __shared__ __attribute__((aligned(16))) bf16_t As[128 * 64];
  __shared__ __attribute__((aligned(16))) bf16_t Bs[128 * 64];
  const int tid = threadIdx.x;
  const int w = tid >> 6, lane = tid & 63;
  const int quad = lane >> 4, l16 = lane & 15;
  const int m0 = blockIdx.x * 128, n0 = blockIdx.y * 128;
  const int wm = (w >> 1) * 64, wn = (w & 1) * 64;
  const size_t Kz = (size_t)K;

  f32x4 acc[4][4] = {};

  const bf16_t* Ag = A + (size_t)(m0 + w * 32 + (lane >> 3)) * Kz + (lane & 7) * 8;
  const bf16_t* Bg = B + (size_t)(n0 + w * 32 + (lane >> 3)) * Kz + (lane & 7) * 8;
  bf16_t* Asw = &As[(w * 32) * 64];
  bf16_t* Bsw = &Bs[(w * 32) * 64];

  for (int k0 = 0; k0 < K; k0 += 64) {
#pragma unroll
    for (int i = 0; i < 4; ++i) {
      gload_lds16(Ag + (size_t)i * 8 * Kz + k0, Asw + i * 8 * 64);
      gload_lds16(Bg + (size_t)i * 8 * Kz + k0, Bsw + i * 8 * 64);
    }
    __syncthreads();
#pragma unroll
    for (int kc = 0; kc < 2; ++kc) {
      bf16x8 af[4], bfr[4];
#pragma unroll
      for (int i = 0; i < 4; ++i) {
        af[i]  = *(const bf16x8*)&As[(wm + i * 16 + l16) * 64 + kc * 32 + quad * 8];
        bfr[i] = *(const bf16x8*)&Bs[(wn + i * 16 + l16) * 64 + kc * 32 + quad * 8];
      }
#pragma unroll
      for (int mi = 0; mi < 4; ++mi)
#pragma unroll
        for (int ni = 0; ni < 4; ++ni)
          acc[mi][ni] = MFMA_BF16(af[mi], bfr[ni], acc[mi][ni]);
    }
    __syncthreads();
  }

#pragma unroll
  for (int ni = 0; ni < 4; ++ni) {
    const int col = n0 + wn + ni * 16 + l16;
    const float bv = bias[col];
#pragma unroll
    for (int mi = 0; mi < 4; ++mi) {
#pragma unroll
      for (int r = 0; r < 4; ++r) {
        const int row = m0 + wm + mi * 16 + quad * 4 + r;
        float v = acc[mi][ni][r] + bv;
        if constexpr (EPI == EPI_GELU)
          v = 0.5f * v * (1.0f + erff(v * 0.70710678118654752f));
        if constexpr (EPI == EPI_RES)
          v += res[(size_t)row * N + col];
        if constexpr (EPI == EPI_BF16 || EPI == EPI_GELU)
          obf[(size_t)row * N + col] = (bf16_t)v;
        else
          of32[(size_t)row * N + col] = v;
      }
    }
  }
}

// ---------------- V transpose: qkv V-part [tok][h*64+d] -> Vt[bh][d][s] -----
__global__ __launch_bounds__(256)
void vtrans_kernel(const bf16_t* __restrict__ qkv, bf16_t* __restrict__ Vt) {
  __shared__ bf16_t tile[64][72];
  const int bh = blockIdx.y;
  const int b = bh >> 4, h = bh & 15;
  const int s0 = blockIdx.x * 64;
  const int c = threadIdx.x & 63, rb = threadIdx.x >> 6;
#pragma unroll
  for (int i = 0; i < 16; ++i) {
    int r = i * 4 + rb;                       // s-local
    tile[r][c] = qkv[(size_t)(b * SEQ + s0 + r) * 3072 + 2048 + h * 64 + c];
  }
  __syncthreads();
#pragma unroll
  for (int i = 0; i < 16; ++i) {
    int r = i * 4 + rb;                       // d index
    Vt[((size_t)bh * 64 + r) * SEQ + s0 + c] = tile[c][r];
  }
}

// ---------------- flash attention, causal + key pad mask --------------------
// R4: block = (bh, strip): 128 q-rows, 4 waves x 32 rows (2 sub-tiles/wave
// sharing every K/V fragment). Fixed-shift softmax: p = exp(s + mask), mask
// = -30 (soft), l accumulated via MFMA against an all-ones B fragment.
// Zero cross-lane ops. Grid y reversed so longest strips dispatch first
// (greedy LPT over the causal triangle; 512 blocks, 2/CU).
__global__ __launch_bounds__(256, 2)
void attn_kernel(const bf16_t* __restrict__ qkv, const bf16_t* __restrict__ Vt,
                 const int* __restrict__ tokens, bf16_t* __restrict__ attnb) {
  __shared__ __attribute__((aligned(16))) bf16_t Ks[128 * 64];     // [key][d] swizzled
  __shared__ __attribute__((aligned(16))) bf16_t Vts[64 * 136];    // [d][key] padded
  __shared__ __attribute__((aligned(16))) bf16_t Ps[4][32 * 136];  // per-wave P, 32 rows

  const int tid = threadIdx.x;
  const int w = tid >> 6, lane = tid & 63;
  const int quad = lane >> 4, l16 = lane & 15;
  const int bh = blockIdx.x;
  const int strip = 15 - (int)blockIdx.y;    // longest strips first
  const int b = bh >> 4, h = bh & 15;
  const int ntiles = strip + 1;
  const int qrow0 = strip * 128 + w * 32;    // this wave's 32 q-rows

  const bf16_t* Kbase = qkv + (size_t)b * SEQ * 3072 + 1024 + h * 64;
  const bf16_t* Vbase = Vt + (size_t)bh * 64 * SEQ;
  const int*    tokb  = tokens + b * SEQ;
  bf16_t* Pw = Ps[w];

  const int sw_chunk = (lane & 7) ^ ((lane >> 3) & 7);
  const int xr = l16 & 7;

  // Q fragments (A-layout: m=l16, k=quad*8+j), 2 sub-tiles x 2 k-chunks
  bf16x8 qf[2][2];
#pragma unroll
  for (int mi = 0; mi < 2; ++mi) {
    const size_t trow = (size_t)(b * SEQ + qrow0 + mi * 16 + l16) * 3072 + h * 64;
    qf[mi][0] = *(const bf16x8*)(qkv + trow + quad * 8);
    qf[mi][1] = *(const bf16x8*)(qkv + trow + 32 + quad * 8);
  }

  bf16x8 onev;
#pragma unroll
  for (int j = 0; j < 8; ++j) onev[j] = (bf16_t)1.0f;

  f32x4 oacc[2][4] = {};
  f32x4 lacc[2] = {};

  for (int kt = 0; kt < ntiles; ++kt) {
    const int k0 = kt * 128;
    // stage K rows [w*32, w*32+32), swizzled chunks, 16B/lane DMA
    {
      const bf16_t* Kg = Kbase + (size_t)(k0 + w * 32 + (lane >> 3)) * 3072
                         + sw_chunk * 8;
      bf16_t* Kl = &Ks[(w * 32) * 64];
#pragma unroll
      for (int i = 0; i < 4; ++i)
        gload_lds16(Kg + (size_t)i * 8 * 3072, Kl + i * 8 * 64);
    }
    // stage V^T tile (padded stride 136)
#pragma unroll
    for (int i = 0; i < 4; ++i) {
      int idx = i * 256 + tid;
      int d = idx >> 4, c = idx & 15;
      uint4 v = *(const uint4*)(Vbase + (size_t)d * SEQ + k0 + c * 8);
      *(uint4*)&Vts[d * 136 + c * 8] = v;
    }
    __syncthreads();

    float padneg[8];
#pragma unroll
    for (int ni = 0; ni < 8; ++ni)
      padneg[ni] = (tokb[k0 + ni * 16 + l16] == 0) ? MASKV : 0.0f;

    const bool diag = (kt == ntiles - 1);

    // --- scores for both sub-tiles; kf loaded once, used twice ---
    f32x4 sc0[8] = {}, sc1[8] = {};
#pragma unroll
    for (int kc = 0; kc < 2; ++kc)
#pragma unroll
      for (int ni = 0; ni < 8; ++ni) {
        bf16x8 kf = *(const bf16x8*)&Ks[(ni * 16 + l16) * 64
                                        + ((kc * 4 + quad) ^ xr) * 8];
        sc0[ni] = MFMA_BF16(qf[0][kc], kf, sc0[ni]);
        sc1[ni] = MFMA_BF16(qf[1][kc], kf, sc1[ni]);
      }

    // --- scale + soft masks + exp; write P (no reductions needed) ---
#pragma unroll
    for (int mi = 0; mi < 2; ++mi) {
      f32x4* sc = mi ? sc1 : sc0;
      const int qg = qrow0 + mi * 16 + quad * 4;   // rows qg..qg+3
#pragma unroll
      for (int ni = 0; ni < 8; ++ni) {
        const int key = k0 + ni * 16 + l16;
#pragma unroll
        for (int r = 0; r < 4; ++r) {
          float v = sc[ni][r] * 0.125f + padneg[ni];
          if (diag && key > qg + r) v += MASKV;
          Pw[(mi * 16 + quad * 4 + r) * 136 + ni * 16 + l16] = (bf16_t)__expf(v);
        }
      }
    }

    // --- P @ V + row-sum via ones-MFMA (all on matrix pipe) ---
#pragma unroll
    for (int kc2 = 0; kc2 < 4; ++kc2) {
      bf16x8 pf0 = *(const bf16x8*)&Pw[l16 * 136 + kc2 * 32 + quad * 8];
      bf16x8 pf1 = *(const bf16x8*)&Pw[(16 + l16) * 136 + kc2 * 32 + quad * 8];
      lacc[0] = MFMA_BF16(pf0, onev, lacc[0]);
      lacc[1] = MFMA_BF16(pf1, onev, lacc[1]);
#pragma unroll
      for (int nd = 0; nd < 4; ++nd) {
        bf16x8 vf = *(const bf16x8*)&Vts[(nd * 16 + l16) * 136
                                         + kc2 * 32 + quad * 8];
        oacc[0][nd] = MFMA_BF16(pf0, vf, oacc[0][nd]);
        oacc[1][nd] = MFMA_BF16(pf1, vf, oacc[1][nd]);
      }
    }
    __syncthreads();
  }

  // normalize and write attn output [tok][h*64+d] bf16
#pragma unroll
  for (int mi = 0; mi < 2; ++mi)
#pragma unroll
    for (int r = 0; r < 4; ++r) {
      const int q = qrow0 + mi * 16 + quad * 4 + r;
      const float invl = 1.0f / lacc[mi][r];
#pragma unroll
      for (int nd = 0; nd < 4; ++nd)
        attnb[(size_t)(b * SEQ + q) * DMODEL + h * 64 + nd * 16 + l16] =
            (bf16_t)(oacc[mi][nd][r] * invl);
    }
}

// ---------------------------------------------------------------------------
extern "C" void kernel_launch(void* const* d_in, const int* in_sizes, int n_in,
                              void* d_out, int out_size, void* d_ws, size_t ws_size,
                              hipStream_t stream) {
  const int*   tokens = (const int*)d_in[0];
  const float* emb    = (const float*)d_in[1];
  const float* pos    = (const float*)d_in[2];
  const float* ln1g   = (const float*)d_in[3];
  const float* ln1b   = (const float*)d_in[4];
  const float* ln2g   = (const float*)d_in[5];
  const float* ln2b   = (const float*)d_in[6];
  const float* ln3g   = (const float*)d_in[7];
  const float* ln3b   = (const float*)d_in[8];
  const float* Wq     = (const float*)d_in[9];
  const float* bq     = (const float*)d_in[10];
  const float* Wk     = (const float*)d_in[11];
  const float* bk     = (const float*)d_in[12];
  const float* Wv     = (const float*)d_in[13];
  const float* bv     = (const float*)d_in[14];
  const float* Wo     = (const float*)d_in[15];
  const float* bo     = (const float*)d_in[16];
  const float* W1     = (const float*)d_in[17];
  const float* b1     = (const float*)d_in[18];
  const float* W2     = (const float*)d_in[19];
  const float* b2     = (const float*)d_in[20];
  float* out = (float*)d_out;

  char* p = (char*)d_ws;
  auto alloc = [&](size_t bytes) {
    char* q = p; p += (bytes + 255) & ~(size_t)255; return q;
  };
  float*  x_ln   = (float*)alloc((size_t)NTOK * DMODEL * 4);
  bf16_t* x_lnb  = (bf16_t*)alloc((size_t)NTOK * DMODEL * 2);
  bf16_t* WqkvT  = (bf16_t*)alloc((size_t)3072 * 1024 * 2);
  float*  bqkv   = (float*)alloc(3072 * 4);
  bf16_t* WoT    = (bf16_t*)alloc((size_t)1024 * 1024 * 2);
  bf16_t* W1T    = (bf16_t*)alloc((size_t)4096 * 1024 * 2);
  bf16_t* W2T    = (bf16_t*)alloc((size_t)1024 * 4096 * 2);
  bf16_t* qkvb   = (bf16_t*)alloc((size_t)NTOK * 3072 * 2);
  bf16_t* Vtb    = (bf16_t*)alloc((size_t)32 * 64 * SEQ * 2);
  bf16_t* attnb  = (bf16_t*)alloc((size_t)NTOK * DMODEL * 2);
  float*  attn_o = (float*)alloc((size_t)NTOK * DMODEL * 4);
  float*  x2     = (float*)alloc((size_t)NTOK * DMODEL * 4);
  bf16_t* x3b    = (bf16_t*)alloc((size_t)NTOK * DMODEL * 2);
  bf16_t* hbuf   = (bf16_t*)alloc((size_t)NTOK * 4096 * 2);

  // weight prep (re-done every call; ws is re-poisoned by harness)
  wtrans_kernel<<<dim3(16, 16), 256, 0, stream>>>(Wq, WqkvT,                 1024, 1024);
  wtrans_kernel<<<dim3(16, 16), 256, 0, stream>>>(Wk, WqkvT + 1024ull * 1024, 1024, 1024);
  wtrans_kernel<<<dim3(16, 16), 256, 0, stream>>>(Wv, WqkvT + 2048ull * 1024, 1024, 1024);
  wtrans_kernel<<<dim3(16, 16), 256, 0, stream>>>(Wo, WoT, 1024, 1024);
  wtrans_kernel<<<dim3(64, 16), 256, 0, stream>>>(W1, W1T, 1024, 4096);
  wtrans_kernel<<<dim3(16, 64), 256, 0, stream>>>(W2, W2T, 4096, 1024);
  pack_bias_kernel<<<4, 256, 0, stream>>>(bq, bk, bv, bqkv);

  // embed + LN1
  ln1_kernel<<<NTOK, 256, 0, stream>>>(tokens, emb, pos, ln1g, ln1b, x_ln, x_lnb);

  // QKV projection (packed N=3072)
  gemm_bt<EPI_BF16><<<dim3(32, 24), 256, 0, stream>>>(
      x_lnb, WqkvT, bqkv, nullptr, qkvb, nullptr, NTOK, 3072, 1024);

  // V transpose for PV MFMA
  vtrans_kernel<<<dim3(32, 32), 256, 0, stream>>>(qkvb, Vtb);

  // flash attention (128-row strips, longest-first LPT)
  attn_kernel<<<dim3(32, 16), 256, 0, stream>>>(qkvb, Vtb, tokens, attnb);

  // output projection
  gemm_bt<EPI_F32><<<dim3(32, 8), 256, 0, stream>>>(
      attnb, WoT, bo, nullptr, nullptr, attn_o, NTOK, 1024, 1024);

  // x2 = x_ln + LN2(attn_out);  x3b = bf16(LN3(x2))
  ln23_kernel<<<NTOK, 256, 0, stream>>>(attn_o, x_ln, ln2g, ln2b, ln3g, ln3b, x2, x3b);

  // FFN up + exact GELU
  gemm_bt<EPI_GELU><<<dim3(32, 32), 256, 0, stream>>>(
      x3b, W1T, b1, nullptr, hbuf, nullptr, NTOK, 4096, 1024);

  // FFN down + residual -> out
  gemm_bt<EPI_RES><<<dim3(32, 8), 256, 0, stream>>>(
      hbuf, W2T, b2, x2, nullptr, out, NTOK, 1024, 4096);

  (void)in_sizes; (void)n_in; (void)out_size; (void)ws_size;
}